// Round 2
// baseline (664.609 us; speedup 1.0000x reference)
//
#include <hip/hip_runtime.h>
#include <hip/hip_bf16.h>

typedef __bf16 bf16x8 __attribute__((ext_vector_type(8)));
typedef float f32x4 __attribute__((ext_vector_type(4)));
typedef __hip_bfloat16 bf16;

// async 16B global -> LDS (lds dest = wave-uniform base + lane*16)
#define GLOAD_LDS16(g, l)                                               \
  __builtin_amdgcn_global_load_lds(                                     \
      (__attribute__((address_space(1))) void*)(void*)(g),              \
      (__attribute__((address_space(3))) void*)(void*)(l), 16, 0, 0)

// ---------------------------------------------------------------------------
// fp32 -> bf16 bulk convert (n multiple of 4)
// ---------------------------------------------------------------------------
__global__ __launch_bounds__(256) void cvt_f32_bf16(
    const float4* __restrict__ src, ushort4* __restrict__ dst, int n4)
{
  const int i = blockIdx.x * 256 + threadIdx.x;
  if (i < n4) {
    float4 v = src[i];
    bf16 b0 = __float2bfloat16(v.x), b1 = __float2bfloat16(v.y);
    bf16 b2 = __float2bfloat16(v.z), b3 = __float2bfloat16(v.w);
    ushort4 o;
    o.x = *(unsigned short*)&b0; o.y = *(unsigned short*)&b1;
    o.z = *(unsigned short*)&b2; o.w = *(unsigned short*)&b3;
    dst[i] = o;
  }
}

// ---------------------------------------------------------------------------
// GEMM: C[M,N] = A[M,K] * W[N,K]^T   bf16 in, fp32 accum, OutT out
// 128x128 tile, BK=32, 4 waves each 64x64 (4x4 fragments of 16x16x32)
// ---------------------------------------------------------------------------
__device__ __forceinline__ void store_out(bf16* p, float v)  { *p = __float2bfloat16(v); }
__device__ __forceinline__ void store_out(float* p, float v) { *p = v; }

template <typename OutT>
__device__ __forceinline__ void gemm_tile_body(
    const bf16* __restrict__ A, const bf16* __restrict__ W, OutT* __restrict__ C,
    int bm, int bn, int N, int K, bf16* As, bf16* Ws)
{
  const int tid  = threadIdx.x;
  const int lane = tid & 63;
  const int wave = tid >> 6;
  const int wm = (wave >> 1) * 64;
  const int wn = (wave & 1) * 64;
  const int mfrag = lane & 15;
  const int kfrag = (lane >> 4) * 8;

  f32x4 acc[4][4] = {};

  for (int k0 = 0; k0 < K; k0 += 32) {
#pragma unroll
    for (int r = 0; r < 2; ++r) {
      const int off  = r * 4096 + wave * 1024 + lane * 16;  // byte off in 8KB tile
      const int row  = off >> 6;                            // 64 B per row (BK=32 bf16)
      const int colb = off & 63;
      const char* ga = (const char*)A + ((size_t)(bm + row) * K + k0) * 2 + colb;
      GLOAD_LDS16(ga, (char*)As + r * 4096 + wave * 1024);
      const char* gw = (const char*)W + ((size_t)(bn + row) * K + k0) * 2 + colb;
      GLOAD_LDS16(gw, (char*)Ws + r * 4096 + wave * 1024);
    }
    __syncthreads();

    bf16x8 af[4], wf[4];
#pragma unroll
    for (int i = 0; i < 4; ++i)
      af[i] = *(const bf16x8*)(As + (wm + i * 16 + mfrag) * 32 + kfrag);
#pragma unroll
    for (int j = 0; j < 4; ++j)
      wf[j] = *(const bf16x8*)(Ws + (wn + j * 16 + mfrag) * 32 + kfrag);
#pragma unroll
    for (int i = 0; i < 4; ++i)
#pragma unroll
      for (int j = 0; j < 4; ++j)
        acc[i][j] = __builtin_amdgcn_mfma_f32_16x16x32_bf16(af[i], wf[j], acc[i][j], 0, 0, 0);
    __syncthreads();
  }

  const int rq = (lane >> 4) * 4;
#pragma unroll
  for (int i = 0; i < 4; ++i)
#pragma unroll
    for (int j = 0; j < 4; ++j)
#pragma unroll
      for (int r = 0; r < 4; ++r) {
        const int row = bm + wm + i * 16 + rq + r;
        const int col = bn + wn + j * 16 + mfrag;
        store_out(&C[(size_t)row * N + col], acc[i][j][r]);
      }
}

__global__ __launch_bounds__(256) void gemm_bt_f32out(
    const bf16* __restrict__ A, const bf16* __restrict__ W, float* __restrict__ C,
    int N, int K)
{
  __shared__ bf16 As[128 * 32];
  __shared__ bf16 Ws[128 * 32];
  gemm_tile_body<float>(A, W, C, blockIdx.y * 128, blockIdx.x * 128, N, K, As, Ws);
}

// fused QKV: grid.x = 16(Q) + 4(K) + 4(V) column-blocks
__global__ __launch_bounds__(256) void gemm_qkv(
    const bf16* __restrict__ X, const bf16* __restrict__ Wq,
    const bf16* __restrict__ Wk, const bf16* __restrict__ Wv,
    bf16* __restrict__ Qo, bf16* __restrict__ Ko, bf16* __restrict__ Vo, int K)
{
  __shared__ bf16 As[128 * 32];
  __shared__ bf16 Ws[128 * 32];
  const int bx = blockIdx.x;
  const bf16* W; bf16* C; int N, bn;
  if (bx < 16)      { W = Wq; C = Qo; N = 2048; bn = bx * 128; }
  else if (bx < 20) { W = Wk; C = Ko; N = 512;  bn = (bx - 16) * 128; }
  else              { W = Wv; C = Vo; N = 512;  bn = (bx - 20) * 128; }
  gemm_tile_body<bf16>(X, W, C, blockIdx.y * 128, bn, N, K, As, Ws);
}

// ---------------------------------------------------------------------------
// RMSNorm + RoPE (+ gain + 1/sqrt(D) folded), in place. One wave per (b,t,h).
// lane j holds the rotary pair (j, j+64). gain is fp32 (or null).
// ---------------------------------------------------------------------------
__global__ __launch_bounds__(256) void rmsrope_kernel(
    bf16* __restrict__ buf, const float* __restrict__ gain,
    int nh, float scale, int nrows)
{
  const int row = blockIdx.x * 4 + (threadIdx.x >> 6);
  const int j = threadIdx.x & 63;
  if (row >= nrows) return;
  const int bt = row / nh;
  const int h  = row - bt * nh;
  const int t  = bt & 2047;  // T = 2048
  bf16* p = buf + (size_t)bt * (nh * 128) + h * 128;

  float x1 = __bfloat162float(p[j]);
  float x2 = __bfloat162float(p[j + 64]);
  float ss = x1 * x1 + x2 * x2;
#pragma unroll
  for (int off = 32; off > 0; off >>= 1) ss += __shfl_xor(ss, off, 64);
  const float rinv = rsqrtf(ss * (1.0f / 128.0f) + 1.1920928955078125e-07f);
  const float g = gain ? gain[h] : 1.0f;
  const float s = rinv * g * scale;

  // base = 10000 * 2^(128/126)  (T=2048 > TRAIN=1024); log2(base) = 14.303585395422464
  const float inv_freq = exp2f(-(float)j * (14.3035853954f / 64.0f));
  const float fr = (float)t * inv_freq;
  const float cs = cosf(fr), sn = sinf(fr);
  const float o1 = s * (x1 * cs + x2 * sn);
  const float o2 = s * (x2 * cs - x1 * sn);
  p[j]      = __float2bfloat16(o1);
  p[j + 64] = __float2bfloat16(o2);
}

// ---------------------------------------------------------------------------
// MFMA flash attention, causal, GQA (kv head = h>>2). BQ=64/block (4 waves x
// 16 q-rows), BKV=64. Q pre-scaled by rmsnorm*gain/sqrt(D).
// ---------------------------------------------------------------------------
__global__ __launch_bounds__(256) void flash_attn(
    const bf16* __restrict__ Q, const bf16* __restrict__ Kg,
    const bf16* __restrict__ Vg, bf16* __restrict__ Y)
{
  __shared__ bf16 Ks[64 * 136];     // [key][d], stride 136
  __shared__ bf16 Vt[128 * 72];     // [d][key] transposed, stride 72
  __shared__ bf16 Ps[4][16 * 72];   // per-wave P, [q][k], stride 72

  const int tid  = threadIdx.x;
  const int lane = tid & 63;
  const int w    = tid >> 6;
  const int qt = 31 - (blockIdx.x & 31);   // reversed: heavy blocks first
  const int h  = (blockIdx.x >> 5) & 15;
  const int b  = blockIdx.x >> 9;
  const int kvh = h >> 2;
  const int mfrag = lane & 15;
  const int quad  = lane >> 4;
  const int kfrag = quad * 8;

  bf16x8 qf[4];
  {
    const bf16* qrow = Q + ((size_t)(b * 2048 + qt * 64 + w * 16 + mfrag)) * 2048 + h * 128;
#pragma unroll
    for (int c = 0; c < 4; ++c) qf[c] = *(const bf16x8*)(qrow + c * 32 + kfrag);
  }

  f32x4 o[8] = {};
  float m_run[4], l_run[4];
#pragma unroll
  for (int r = 0; r < 4; ++r) { m_run[r] = -1e30f; l_run[r] = 0.f; }
  const int q_base = qt * 64 + w * 16 + quad * 4;  // + r

  for (int kt = 0; kt <= qt; ++kt) {
    // ---- stage K tile and transposed V tile
#pragma unroll
    for (int r4 = 0; r4 < 4; ++r4) {
      const int id = r4 * 256 + tid;
      const int key = id >> 4;
      const int c = id & 15;
      const size_t grow = (size_t)(b * 2048 + kt * 64 + key) * 512 + kvh * 128 + c * 8;
      *(float4*)((char*)Ks + key * 272 + c * 16) = *(const float4*)(const void*)(Kg + grow);
      float4 vv = *(const float4*)(const void*)(Vg + grow);
      const bf16* v8 = (const bf16*)&vv;
#pragma unroll
      for (int i = 0; i < 8; ++i) Vt[(c * 8 + i) * 72 + key] = v8[i];
    }
    __syncthreads();

    // ---- S = Q K^T (C-layout: row q = quad*4+r, col k = mfrag + kc*16)
    f32x4 s[4] = {};
#pragma unroll
    for (int kc = 0; kc < 4; ++kc)
#pragma unroll
      for (int c = 0; c < 4; ++c) {
        bf16x8 kf = *(const bf16x8*)(Ks + (kc * 16 + mfrag) * 136 + c * 32 + kfrag);
        s[kc] = __builtin_amdgcn_mfma_f32_16x16x32_bf16(qf[c], kf, s[kc], 0, 0, 0);
      }

    // ---- causal mask
    const int kcol0 = kt * 64 + mfrag;
#pragma unroll
    for (int kc = 0; kc < 4; ++kc)
#pragma unroll
      for (int r = 0; r < 4; ++r)
        if (kcol0 + kc * 16 > q_base + r) s[kc][r] = -1e30f;

    // ---- online softmax (row stats via 16-lane butterflies)
    float mnew[4], alpha[4], rs[4];
#pragma unroll
    for (int r = 0; r < 4; ++r) {
      float tm = fmaxf(fmaxf(s[0][r], s[1][r]), fmaxf(s[2][r], s[3][r]));
#pragma unroll
      for (int off = 1; off < 16; off <<= 1) tm = fmaxf(tm, __shfl_xor(tm, off, 64));
      mnew[r]  = fmaxf(m_run[r], tm);
      alpha[r] = __expf(m_run[r] - mnew[r]);
      rs[r] = 0.f;
    }
    bf16* psw = &Ps[w][0];
#pragma unroll
    for (int kc = 0; kc < 4; ++kc)
#pragma unroll
      for (int r = 0; r < 4; ++r) {
        const float pv = __expf(s[kc][r] - mnew[r]);
        rs[r] += pv;
        psw[(quad * 4 + r) * 72 + kc * 16 + mfrag] = __float2bfloat16(pv);
      }
#pragma unroll
    for (int r = 0; r < 4; ++r) {
#pragma unroll
      for (int off = 1; off < 16; off <<= 1) rs[r] += __shfl_xor(rs[r], off, 64);
      l_run[r] = l_run[r] * alpha[r] + rs[r];
      m_run[r] = mnew[r];
    }
#pragma unroll
    for (int dc = 0; dc < 8; ++dc)
#pragma unroll
      for (int r = 0; r < 4; ++r) o[dc][r] *= alpha[r];

    __syncthreads();  // P visible (C-layout write -> A-layout read)

    // ---- O += P V  (A = P rows [q][k], B^T = Vt rows [d][key])
#pragma unroll
    for (int kh = 0; kh < 2; ++kh) {
      bf16x8 pf = *(const bf16x8*)(psw + mfrag * 72 + kh * 32 + kfrag);
#pragma unroll
      for (int dc = 0; dc < 8; ++dc) {
        bf16x8 vf = *(const bf16x8*)(Vt + (dc * 16 + mfrag) * 72 + kh * 32 + kfrag);
        o[dc] = __builtin_amdgcn_mfma_f32_16x16x32_bf16(pf, vf, o[dc], 0, 0, 0);
      }
    }
    __syncthreads();  // all reads done before next stage overwrites tiles
  }

  // ---- epilogue
#pragma unroll
  for (int r = 0; r < 4; ++r) {
    const float linv = 1.0f / l_run[r];
    const size_t row = (size_t)(b * 2048 + q_base + r);
#pragma unroll
    for (int dc = 0; dc < 8; ++dc)
      Y[row * 2048 + h * 128 + dc * 16 + mfrag] = __float2bfloat16(o[dc][r] * linv);
  }
}

// ---------------------------------------------------------------------------
extern "C" void kernel_launch(void* const* d_in, const int* in_sizes, int n_in,
                              void* d_out, int out_size, void* d_ws, size_t ws_size,
                              hipStream_t stream)
{
  const float* x      = (const float*)d_in[0];
  const float* q_w    = (const float*)d_in[1];
  const float* k_w    = (const float*)d_in[2];
  const float* v_w    = (const float*)d_in[3];
  const float* o_w    = (const float*)d_in[4];
  const float* q_gain = (const float*)d_in[5];
  float* out = (float*)d_out;

  // workspace layout (bf16 buffers); xb aliases yb (x dead after QKV GEMM)
  char* ws = (char*)d_ws;
  bf16* xb  = (bf16*)(ws);                   // 4096x2048 = 16 MB (aliased w/ yb)
  bf16* yb  = (bf16*)(ws);                   //
  bf16* qwb = (bf16*)(ws + (16u << 20));     // 2048x2048 = 8 MB
  bf16* owb = (bf16*)(ws + (24u << 20));     // 2048x2048 = 8 MB
  bf16* kwb = (bf16*)(ws + (32u << 20));     // 512x2048  = 2 MB
  bf16* vwb = (bf16*)(ws + (34u << 20));     // 512x2048  = 2 MB
  bf16* qb  = (bf16*)(ws + (36u << 20));     // 4096x2048 = 16 MB
  bf16* kb  = (bf16*)(ws + (52u << 20));     // 4096x512  = 4 MB
  bf16* vb  = (bf16*)(ws + (56u << 20));     // 4096x512  = 4 MB  (total 60 MB)

  const dim3 blk(256);
  cvt_f32_bf16<<<dim3(8192), blk, 0, stream>>>((const float4*)x,   (ushort4*)xb,  2097152);
  cvt_f32_bf16<<<dim3(4096), blk, 0, stream>>>((const float4*)q_w, (ushort4*)qwb, 1048576);
  cvt_f32_bf16<<<dim3(1024), blk, 0, stream>>>((const float4*)k_w, (ushort4*)kwb, 262144);
  cvt_f32_bf16<<<dim3(1024), blk, 0, stream>>>((const float4*)v_w, (ushort4*)vwb, 262144);
  cvt_f32_bf16<<<dim3(4096), blk, 0, stream>>>((const float4*)o_w, (ushort4*)owb, 1048576);

  gemm_qkv<<<dim3(24, 32), blk, 0, stream>>>(xb, qwb, kwb, vwb, qb, kb, vb, 2048);
  // Q: fold gain * 1/sqrt(128); K: plain rmsnorm+rope
  rmsrope_kernel<<<dim3(16384), blk, 0, stream>>>(qb, q_gain, 16, 0.08838834764831845f, 65536);
  rmsrope_kernel<<<dim3(4096),  blk, 0, stream>>>(kb, nullptr, 4, 1.0f, 16384);
  flash_attn<<<dim3(1024), blk, 0, stream>>>(qb, kb, vb, yb);
  gemm_bt_f32out<<<dim3(16, 32), blk, 0, stream>>>(yb, owb, out, 2048, 2048);
}

// Round 3
// 359.353 us; speedup vs baseline: 1.8495x; 1.8495x over previous
//
#include <hip/hip_runtime.h>
#include <hip/hip_bf16.h>

typedef __bf16 bf16x8 __attribute__((ext_vector_type(8)));
typedef unsigned short u16x8 __attribute__((ext_vector_type(8)));
typedef float f32x4 __attribute__((ext_vector_type(4)));
typedef __hip_bfloat16 bf16;

// async 16B global -> LDS (lds dest = wave-uniform base + lane*16)
#define GLOAD_LDS16(g, l)                                               \
  __builtin_amdgcn_global_load_lds(                                     \
      (__attribute__((address_space(1))) void*)(void*)(g),              \
      (__attribute__((address_space(3))) void*)(void*)(l), 16, 0, 0)

// ---------------------------------------------------------------------------
// fp32 -> bf16 bulk convert (n multiple of 4)
// ---------------------------------------------------------------------------
__global__ __launch_bounds__(256) void cvt_f32_bf16(
    const float4* __restrict__ src, ushort4* __restrict__ dst, int n4)
{
  const int i = blockIdx.x * 256 + threadIdx.x;
  if (i < n4) {
    float4 v = src[i];
    bf16 b0 = __float2bfloat16(v.x), b1 = __float2bfloat16(v.y);
    bf16 b2 = __float2bfloat16(v.z), b3 = __float2bfloat16(v.w);
    ushort4 o;
    o.x = *(unsigned short*)&b0; o.y = *(unsigned short*)&b1;
    o.z = *(unsigned short*)&b2; o.w = *(unsigned short*)&b3;
    dst[i] = o;
  }
}

// ---------------------------------------------------------------------------
// V[4096][512] -> Vt[512][4096]. Reads 16B/lane; stores coalesce per
// instruction (64 consecutive lanes write 64 consecutive t for fixed d).
// ---------------------------------------------------------------------------
__global__ __launch_bounds__(256) void transpose_v(
    const unsigned short* __restrict__ V, unsigned short* __restrict__ Vt)
{
  const int idx = blockIdx.x * 256 + threadIdx.x;   // 256K threads
  const int t  = idx & 4095;
  const int dc = idx >> 12;                          // [0,64)
  u16x8 v = *(const u16x8*)(V + (size_t)t * 512 + dc * 8);
#pragma unroll
  for (int j = 0; j < 8; ++j)
    Vt[(size_t)(dc * 8 + j) * 4096 + t] = v[j];
}

// ---------------------------------------------------------------------------
// GEMM: C[M,N] = A[M,K] * W[N,K]^T   bf16 in, fp32 accum, OutT out
// ---------------------------------------------------------------------------
__device__ __forceinline__ void store_out(bf16* p, float v)  { *p = __float2bfloat16(v); }
__device__ __forceinline__ void store_out(float* p, float v) { *p = v; }

template <typename OutT>
__device__ __forceinline__ void gemm_tile_body(
    const bf16* __restrict__ A, const bf16* __restrict__ W, OutT* __restrict__ C,
    int bm, int bn, int N, int K, bf16* As, bf16* Ws)
{
  const int tid  = threadIdx.x;
  const int lane = tid & 63;
  const int wave = tid >> 6;
  const int wm = (wave >> 1) * 64;
  const int wn = (wave & 1) * 64;
  const int mfrag = lane & 15;
  const int kfrag = (lane >> 4) * 8;

  f32x4 acc[4][4] = {};

  for (int k0 = 0; k0 < K; k0 += 32) {
#pragma unroll
    for (int r = 0; r < 2; ++r) {
      const int off  = r * 4096 + wave * 1024 + lane * 16;
      const int row  = off >> 6;
      const int colb = off & 63;
      const char* ga = (const char*)A + ((size_t)(bm + row) * K + k0) * 2 + colb;
      GLOAD_LDS16(ga, (char*)As + r * 4096 + wave * 1024);
      const char* gw = (const char*)W + ((size_t)(bn + row) * K + k0) * 2 + colb;
      GLOAD_LDS16(gw, (char*)Ws + r * 4096 + wave * 1024);
    }
    __syncthreads();

    bf16x8 af[4], wf[4];
#pragma unroll
    for (int i = 0; i < 4; ++i)
      af[i] = *(const bf16x8*)(As + (wm + i * 16 + mfrag) * 32 + kfrag);
#pragma unroll
    for (int j = 0; j < 4; ++j)
      wf[j] = *(const bf16x8*)(Ws + (wn + j * 16 + mfrag) * 32 + kfrag);
#pragma unroll
    for (int i = 0; i < 4; ++i)
#pragma unroll
      for (int j = 0; j < 4; ++j)
        acc[i][j] = __builtin_amdgcn_mfma_f32_16x16x32_bf16(af[i], wf[j], acc[i][j], 0, 0, 0);
    __syncthreads();
  }

  const int rq = (lane >> 4) * 4;
#pragma unroll
  for (int i = 0; i < 4; ++i)
#pragma unroll
    for (int j = 0; j < 4; ++j)
#pragma unroll
      for (int r = 0; r < 4; ++r) {
        const int row = bm + wm + i * 16 + rq + r;
        const int col = bn + wn + j * 16 + mfrag;
        store_out(&C[(size_t)row * N + col], acc[i][j][r]);
      }
}

__global__ __launch_bounds__(256) void gemm_bt_f32out(
    const bf16* __restrict__ A, const bf16* __restrict__ W, float* __restrict__ C,
    int N, int K)
{
  __shared__ bf16 As[128 * 32];
  __shared__ bf16 Ws[128 * 32];
  gemm_tile_body<float>(A, W, C, blockIdx.y * 128, blockIdx.x * 128, N, K, As, Ws);
}

__global__ __launch_bounds__(256) void gemm_qkv(
    const bf16* __restrict__ X, const bf16* __restrict__ Wq,
    const bf16* __restrict__ Wk, const bf16* __restrict__ Wv,
    bf16* __restrict__ Qo, bf16* __restrict__ Ko, bf16* __restrict__ Vo, int K)
{
  __shared__ bf16 As[128 * 32];
  __shared__ bf16 Ws[128 * 32];
  const int bx = blockIdx.x;
  const bf16* W; bf16* C; int N, bn;
  if (bx < 16)      { W = Wq; C = Qo; N = 2048; bn = bx * 128; }
  else if (bx < 20) { W = Wk; C = Ko; N = 512;  bn = (bx - 16) * 128; }
  else              { W = Wv; C = Vo; N = 512;  bn = (bx - 20) * 128; }
  gemm_tile_body<bf16>(X, W, C, blockIdx.y * 128, bn, N, K, As, Ws);
}

// ---------------------------------------------------------------------------
// RMSNorm + RoPE (+ gain + 1/sqrt(D) folded), in place. One wave per (b,t,h).
// ---------------------------------------------------------------------------
__global__ __launch_bounds__(256) void rmsrope_kernel(
    bf16* __restrict__ buf, const float* __restrict__ gain,
    int nh, float scale, int nrows)
{
  const int row = blockIdx.x * 4 + (threadIdx.x >> 6);
  const int j = threadIdx.x & 63;
  if (row >= nrows) return;
  const int bt = row / nh;
  const int h  = row - bt * nh;
  const int t  = bt & 2047;  // T = 2048
  bf16* p = buf + (size_t)bt * (nh * 128) + h * 128;

  float x1 = __bfloat162float(p[j]);
  float x2 = __bfloat162float(p[j + 64]);
  float ss = x1 * x1 + x2 * x2;
#pragma unroll
  for (int off = 32; off > 0; off >>= 1) ss += __shfl_xor(ss, off, 64);
  const float rinv = rsqrtf(ss * (1.0f / 128.0f) + 1.1920928955078125e-07f);
  const float g = gain ? gain[h] : 1.0f;
  const float s = rinv * g * scale;

  // base = 10000 * 2^(128/126) (T=2048 > TRAIN=1024); log2(base) = 14.3035853954
  const float inv_freq = exp2f(-(float)j * (14.3035853954f / 64.0f));
  const float fr = (float)t * inv_freq;
  const float cs = cosf(fr), sn = sinf(fr);
  p[j]      = __float2bfloat16(s * (x1 * cs + x2 * sn));
  p[j + 64] = __float2bfloat16(s * (x2 * cs - x1 * sn));
}

// ---------------------------------------------------------------------------
// MFMA flash attention v2. Causal, GQA (kv head = h>>2).
// Block = 4 waves = 64 q-rows; processes q-tile pair (31-p, p) sequentially
// (uniform 33 k-tiles/block; 512 blocks = exactly 2/CU at 56 KB LDS).
// K double-buffered + prefetched via global_load_lds; V (pre-transposed in
// global) single-buffered; XOR-swizzled unpadded tiles (conflict-free b128);
// P per-wave private (no barrier). 2 barriers per 64-key tile.
// ---------------------------------------------------------------------------
__global__ __launch_bounds__(256) void flash_attn(
    const bf16* __restrict__ Q, const bf16* __restrict__ Kg,
    const bf16* __restrict__ Vtg, bf16* __restrict__ Y)
{
  __shared__ bf16 Ks[2][64 * 128];  // [key][d], 16B-chunk XOR swizzle, 2x16 KB
  __shared__ bf16 Vs[128 * 64];     // [d][key], swizzled, 16 KB
  __shared__ bf16 Ps[4][16 * 64];   // per-wave P [q][key], swizzled, 8 KB

  const int tid = threadIdx.x, lane = tid & 63, w = tid >> 6;
  const int p = blockIdx.x & 15, bh = blockIdx.x >> 4;
  const int h = bh & 15, b = bh >> 4, kvh = h >> 2;
  const int mfrag = lane & 15, quad = lane >> 4;
  const int m7 = mfrag & 7;

  auto stage_k = [&](int kt, int s) {
#pragma unroll
    for (int g = 0; g < 4; ++g) {
      const int o = g * 4096 + w * 1024 + lane * 16;  // byte offset, 256 B rows
      const int r = o >> 8, c = (o >> 4) & 15;
      const int cs = (c & 8) | ((c ^ (r & 7)) & 7);
      const bf16* src = Kg + ((size_t)(b * 2048 + kt * 64 + r)) * 512 + kvh * 128 + cs * 8;
      GLOAD_LDS16(src, (char*)&Ks[s][0] + g * 4096 + w * 1024);
    }
  };
  auto stage_v = [&](int kt) {
#pragma unroll
    for (int g = 0; g < 4; ++g) {
      const int o = g * 4096 + w * 1024 + lane * 16;  // byte offset, 128 B rows
      const int r = o >> 7, c = (o >> 4) & 7;
      const int cs = (c ^ (r & 7)) & 7;
      const bf16* src = Vtg + ((size_t)(kvh * 128 + r)) * 4096 + b * 2048 + kt * 64 + cs * 8;
      GLOAD_LDS16(src, (char*)Vs + g * 4096 + w * 1024);
    }
  };

  stage_k(0, 0);
  int sb = 0;
  bf16* psw = &Ps[w][0];

  for (int phase = 0; phase < 2; ++phase) {
    const int qt = phase ? p : 31 - p;

    bf16x8 qf[4];
    const bf16* qrow = Q + ((size_t)(b * 2048 + qt * 64 + w * 16 + mfrag)) * 2048 + h * 128;
#pragma unroll
    for (int c = 0; c < 4; ++c) qf[c] = *(const bf16x8*)(qrow + c * 32 + quad * 8);

    f32x4 oacc[8] = {};
    float m_run[4], l_run[4];
#pragma unroll
    for (int r = 0; r < 4; ++r) { m_run[r] = -1e30f; l_run[r] = 0.f; }
    const int q_base = qt * 64 + w * 16 + quad * 4;

    for (int kt = 0; kt <= qt; ++kt) {
      __syncthreads();  // prev tile's PV done (Vs free); Ks[sb] loads drained
      stage_v(kt);
      const bool last = (phase == 1) && (kt == qt);
      if (!last) stage_k(kt < qt ? kt + 1 : 0, sb ^ 1);

      // ---- S = Q K^T  (C-layout: row q = quad*4+r, col key = kc*16+mfrag)
      f32x4 sc[4] = {};
#pragma unroll
      for (int kc = 0; kc < 4; ++kc) {
        const bf16* krow = &Ks[sb][0] + (kc * 16 + mfrag) * 128;
#pragma unroll
        for (int c = 0; c < 4; ++c) {
          const int G = 4 * c + quad;
          const int cs = (G & 8) | ((G ^ m7) & 7);
          bf16x8 kf = *(const bf16x8*)(krow + cs * 8);
          sc[kc] = __builtin_amdgcn_mfma_f32_16x16x32_bf16(qf[c], kf, sc[kc], 0, 0, 0);
        }
      }

      // ---- causal mask (only the diagonal tile needs it)
      if (kt == qt) {
        const int kcol0 = kt * 64 + mfrag;
#pragma unroll
        for (int kc = 0; kc < 4; ++kc)
#pragma unroll
          for (int r = 0; r < 4; ++r)
            if (kcol0 + kc * 16 > q_base + r) sc[kc][r] = -1e30f;
      }

      // ---- online softmax (row stats across the 16 mfrag lanes of each quad)
      float mnew[4], alpha[4];
#pragma unroll
      for (int r = 0; r < 4; ++r) {
        float tm = fmaxf(fmaxf(sc[0][r], sc[1][r]), fmaxf(sc[2][r], sc[3][r]));
        tm = fmaxf(tm, __shfl_xor(tm, 1, 64));
        tm = fmaxf(tm, __shfl_xor(tm, 2, 64));
        tm = fmaxf(tm, __shfl_xor(tm, 4, 64));
        tm = fmaxf(tm, __shfl_xor(tm, 8, 64));
        mnew[r]  = fmaxf(m_run[r], tm);
        alpha[r] = __expf(m_run[r] - mnew[r]);
        m_run[r] = mnew[r];
      }
      float rs[4] = {0.f, 0.f, 0.f, 0.f};
#pragma unroll
      for (int kc = 0; kc < 4; ++kc)
#pragma unroll
        for (int r = 0; r < 4; ++r) {
          const float pv = __expf(sc[kc][r] - mnew[r]);
          rs[r] += pv;
          const int q = quad * 4 + r;
          const int slot = ((2 * kc + (mfrag >> 3)) ^ (q & 7)) & 7;
          psw[q * 64 + slot * 8 + m7] = __float2bfloat16(pv);
        }
#pragma unroll
      for (int r = 0; r < 4; ++r) {
        float t = rs[r];
        t += __shfl_xor(t, 1, 64);
        t += __shfl_xor(t, 2, 64);
        t += __shfl_xor(t, 4, 64);
        t += __shfl_xor(t, 8, 64);
        l_run[r] = l_run[r] * alpha[r] + t;
      }
#pragma unroll
      for (int dc = 0; dc < 8; ++dc)
#pragma unroll
        for (int r = 0; r < 4; ++r) oacc[dc][r] *= alpha[r];

      __syncthreads();  // V tile loads (all waves) drained

      // ---- O += P V  (A = own-wave P rows [q][key], B = Vs rows [d][key])
#pragma unroll
      for (int kh = 0; kh < 2; ++kh) {
        const int Gp = 4 * kh + quad;
        const int sl = (Gp ^ m7) & 7;
        bf16x8 pf = *(const bf16x8*)(psw + mfrag * 64 + sl * 8);
#pragma unroll
        for (int dc = 0; dc < 8; ++dc) {
          bf16x8 vf = *(const bf16x8*)(Vs + (dc * 16 + mfrag) * 64 + sl * 8);
          oacc[dc] = __builtin_amdgcn_mfma_f32_16x16x32_bf16(pf, vf, oacc[dc], 0, 0, 0);
        }
      }
      sb ^= 1;
    }

    // ---- epilogue for this q-tile
#pragma unroll
    for (int r = 0; r < 4; ++r) {
      const float linv = 1.0f / l_run[r];
      const size_t row = (size_t)(b * 2048 + q_base + r);
#pragma unroll
      for (int dc = 0; dc < 8; ++dc)
        Y[row * 2048 + h * 128 + dc * 16 + mfrag] = __float2bfloat16(oacc[dc][r] * linv);
    }
  }
}

// ---------------------------------------------------------------------------
extern "C" void kernel_launch(void* const* d_in, const int* in_sizes, int n_in,
                              void* d_out, int out_size, void* d_ws, size_t ws_size,
                              hipStream_t stream)
{
  const float* x      = (const float*)d_in[0];
  const float* q_w    = (const float*)d_in[1];
  const float* k_w    = (const float*)d_in[2];
  const float* v_w    = (const float*)d_in[3];
  const float* o_w    = (const float*)d_in[4];
  const float* q_gain = (const float*)d_in[5];
  float* out = (float*)d_out;

  // workspace (bf16): xb aliases yb (x dead after QKV GEMM); vtb reuses qwb
  // region (q_w copy dead after QKV GEMM).
  char* ws = (char*)d_ws;
  bf16* xb  = (bf16*)(ws);                   // 4096x2048 = 16 MB
  bf16* yb  = (bf16*)(ws);                   // alias of xb
  bf16* qwb = (bf16*)(ws + (16u << 20));     // 2048x2048 = 8 MB
  bf16* vtb = (bf16*)(ws + (16u << 20));     // 512x4096  = 4 MB (after qwb dead)
  bf16* owb = (bf16*)(ws + (24u << 20));     // 2048x2048 = 8 MB
  bf16* kwb = (bf16*)(ws + (32u << 20));     // 512x2048  = 2 MB
  bf16* vwb = (bf16*)(ws + (34u << 20));     // 512x2048  = 2 MB
  bf16* qb  = (bf16*)(ws + (36u << 20));     // 4096x2048 = 16 MB
  bf16* kb  = (bf16*)(ws + (52u << 20));     // 4096x512  = 4 MB
  bf16* vb  = (bf16*)(ws + (56u << 20));     // 4096x512  = 4 MB  (total 60 MB)

  const dim3 blk(256);
  cvt_f32_bf16<<<dim3(8192), blk, 0, stream>>>((const float4*)x,   (ushort4*)xb,  2097152);
  cvt_f32_bf16<<<dim3(4096), blk, 0, stream>>>((const float4*)q_w, (ushort4*)qwb, 1048576);
  cvt_f32_bf16<<<dim3(1024), blk, 0, stream>>>((const float4*)k_w, (ushort4*)kwb, 262144);
  cvt_f32_bf16<<<dim3(1024), blk, 0, stream>>>((const float4*)v_w, (ushort4*)vwb, 262144);
  cvt_f32_bf16<<<dim3(4096), blk, 0, stream>>>((const float4*)o_w, (ushort4*)owb, 1048576);

  gemm_qkv<<<dim3(24, 32), blk, 0, stream>>>(xb, qwb, kwb, vwb, qb, kb, vb, 2048);
  transpose_v<<<dim3(1024), blk, 0, stream>>>((const unsigned short*)vb, (unsigned short*)vtb);
  rmsrope_kernel<<<dim3(16384), blk, 0, stream>>>(qb, q_gain, 16, 0.08838834764831845f, 65536);
  rmsrope_kernel<<<dim3(4096),  blk, 0, stream>>>(kb, nullptr, 4, 1.0f, 16384);
  flash_attn<<<dim3(512), blk, 0, stream>>>(qb, kb, vtb, yb);
  gemm_bt_f32out<<<dim3(16, 32), blk, 0, stream>>>(yb, owb, out, 2048, 2048);
}

// Round 4
// 323.777 us; speedup vs baseline: 2.0527x; 1.1099x over previous
//
#include <hip/hip_runtime.h>
#include <hip/hip_bf16.h>

typedef __bf16 bf16x8 __attribute__((ext_vector_type(8)));
typedef unsigned short u16x8 __attribute__((ext_vector_type(8)));
typedef float f32x4 __attribute__((ext_vector_type(4)));
typedef __hip_bfloat16 bf16;

// async 16B global -> LDS (lds dest = wave-uniform base + lane*16)
#define GLOAD_LDS16(g, l)                                               \
  __builtin_amdgcn_global_load_lds(                                     \
      (__attribute__((address_space(1))) void*)(void*)(g),              \
      (__attribute__((address_space(3))) void*)(void*)(l), 16, 0, 0)

// ---------------------------------------------------------------------------
// all five fp32 -> bf16 converts in one kernel (range boundaries are
// block-aligned -> wave-uniform branches)
// ---------------------------------------------------------------------------
__global__ __launch_bounds__(256) void cvt_all(
    const float4* __restrict__ x,  const float4* __restrict__ qw,
    const float4* __restrict__ kw, const float4* __restrict__ vw,
    const float4* __restrict__ ow,
    ushort4* __restrict__ xb,  ushort4* __restrict__ qwb,
    ushort4* __restrict__ kwb, ushort4* __restrict__ vwb,
    ushort4* __restrict__ owb)
{
  const int i = blockIdx.x * 256 + threadIdx.x;
  const float4* s; ushort4* d; int off;
  if      (i < 2097152) { s = x;  d = xb;  off = i; }
  else if (i < 3145728) { s = qw; d = qwb; off = i - 2097152; }
  else if (i < 3407872) { s = kw; d = kwb; off = i - 3145728; }
  else if (i < 3670016) { s = vw; d = vwb; off = i - 3407872; }
  else                  { s = ow; d = owb; off = i - 3670016; }
  float4 v = s[off];
  bf16 b0 = __float2bfloat16(v.x), b1 = __float2bfloat16(v.y);
  bf16 b2 = __float2bfloat16(v.z), b3 = __float2bfloat16(v.w);
  ushort4 o;
  o.x = *(unsigned short*)&b0; o.y = *(unsigned short*)&b1;
  o.z = *(unsigned short*)&b2; o.w = *(unsigned short*)&b3;
  d[off] = o;
}

// ---------------------------------------------------------------------------
// GEMM: C[M,N] = A[M,K] * W[N,K]^T   bf16 in, fp32 accum, OutT out
// ---------------------------------------------------------------------------
__device__ __forceinline__ void store_out(bf16* p, float v)  { *p = __float2bfloat16(v); }
__device__ __forceinline__ void store_out(float* p, float v) { *p = v; }

template <typename OutT>
__device__ __forceinline__ void gemm_tile_body(
    const bf16* __restrict__ A, const bf16* __restrict__ W, OutT* __restrict__ C,
    int bm, int bn, int N, int K, bf16* As, bf16* Ws)
{
  const int tid  = threadIdx.x;
  const int lane = tid & 63;
  const int wave = tid >> 6;
  const int wm = (wave >> 1) * 64;
  const int wn = (wave & 1) * 64;
  const int mfrag = lane & 15;
  const int kfrag = (lane >> 4) * 8;

  f32x4 acc[4][4] = {};

  for (int k0 = 0; k0 < K; k0 += 32) {
#pragma unroll
    for (int r = 0; r < 2; ++r) {
      const int off  = r * 4096 + wave * 1024 + lane * 16;
      const int row  = off >> 6;
      const int colb = off & 63;
      const char* ga = (const char*)A + ((size_t)(bm + row) * K + k0) * 2 + colb;
      GLOAD_LDS16(ga, (char*)As + r * 4096 + wave * 1024);
      const char* gw = (const char*)W + ((size_t)(bn + row) * K + k0) * 2 + colb;
      GLOAD_LDS16(gw, (char*)Ws + r * 4096 + wave * 1024);
    }
    __syncthreads();

    bf16x8 af[4], wf[4];
#pragma unroll
    for (int i = 0; i < 4; ++i)
      af[i] = *(const bf16x8*)(As + (wm + i * 16 + mfrag) * 32 + kfrag);
#pragma unroll
    for (int j = 0; j < 4; ++j)
      wf[j] = *(const bf16x8*)(Ws + (wn + j * 16 + mfrag) * 32 + kfrag);
#pragma unroll
    for (int i = 0; i < 4; ++i)
#pragma unroll
      for (int j = 0; j < 4; ++j)
        acc[i][j] = __builtin_amdgcn_mfma_f32_16x16x32_bf16(af[i], wf[j], acc[i][j], 0, 0, 0);
    __syncthreads();
  }

  const int rq = (lane >> 4) * 4;
#pragma unroll
  for (int i = 0; i < 4; ++i)
#pragma unroll
    for (int j = 0; j < 4; ++j)
#pragma unroll
      for (int r = 0; r < 4; ++r) {
        const int row = bm + wm + i * 16 + rq + r;
        const int col = bn + wn + j * 16 + mfrag;
        store_out(&C[(size_t)row * N + col], acc[i][j][r]);
      }
}

__global__ __launch_bounds__(256) void gemm_bt_f32out(
    const bf16* __restrict__ A, const bf16* __restrict__ W, float* __restrict__ C,
    int N, int K)
{
  __shared__ bf16 As[128 * 32];
  __shared__ bf16 Ws[128 * 32];
  gemm_tile_body<float>(A, W, C, blockIdx.y * 128, blockIdx.x * 128, N, K, As, Ws);
}

__global__ __launch_bounds__(256) void gemm_qkv(
    const bf16* __restrict__ X, const bf16* __restrict__ Wq,
    const bf16* __restrict__ Wk, const bf16* __restrict__ Wv,
    bf16* __restrict__ Qo, bf16* __restrict__ Ko, bf16* __restrict__ Vo, int K)
{
  __shared__ bf16 As[128 * 32];
  __shared__ bf16 Ws[128 * 32];
  const int bx = blockIdx.x;
  const bf16* W; bf16* C; int N, bn;
  if (bx < 16)      { W = Wq; C = Qo; N = 2048; bn = bx * 128; }
  else if (bx < 20) { W = Wk; C = Ko; N = 512;  bn = (bx - 16) * 128; }
  else              { W = Wv; C = Vo; N = 512;  bn = (bx - 20) * 128; }
  gemm_tile_body<bf16>(X, W, C, blockIdx.y * 128, bn, N, K, As, Ws);
}

// ---------------------------------------------------------------------------
// post-QKV fixups in one kernel: rope(Q), rope(K), transpose(V)
// ---------------------------------------------------------------------------
__device__ __forceinline__ void rope_row(
    bf16* __restrict__ buf, const float* __restrict__ gain,
    int nh, float scale, int row)
{
  const int j = threadIdx.x & 63;
  const int bt = row / nh;
  const int h  = row - bt * nh;
  const int t  = bt & 2047;  // T = 2048
  bf16* p = buf + (size_t)bt * (nh * 128) + h * 128;

  float x1 = __bfloat162float(p[j]);
  float x2 = __bfloat162float(p[j + 64]);
  float ss = x1 * x1 + x2 * x2;
#pragma unroll
  for (int off = 32; off > 0; off >>= 1) ss += __shfl_xor(ss, off, 64);
  const float rinv = rsqrtf(ss * (1.0f / 128.0f) + 1.1920928955078125e-07f);
  const float g = gain ? gain[h] : 1.0f;
  const float s = rinv * g * scale;

  // base = 10000 * 2^(128/126) (T=2048 > TRAIN=1024); log2(base) = 14.3035853954
  const float inv_freq = exp2f(-(float)j * (14.3035853954f / 64.0f));
  const float fr = (float)t * inv_freq;
  const float cs = cosf(fr), sn = sinf(fr);
  p[j]      = __float2bfloat16(s * (x1 * cs + x2 * sn));
  p[j + 64] = __float2bfloat16(s * (x2 * cs - x1 * sn));
}

__global__ __launch_bounds__(256) void postqkv(
    bf16* __restrict__ qb, bf16* __restrict__ kb,
    const unsigned short* __restrict__ vb, unsigned short* __restrict__ vtb,
    const float* __restrict__ gain)
{
  const int bx = blockIdx.x;
  if (bx < 16384) {
    rope_row(qb, gain, 16, 0.08838834764831845f, bx * 4 + (threadIdx.x >> 6));
  } else if (bx < 20480) {
    rope_row(kb, nullptr, 4, 1.0f, (bx - 16384) * 4 + (threadIdx.x >> 6));
  } else {
    const int idx = (bx - 20480) * 256 + threadIdx.x;  // 256K threads
    const int t  = idx & 4095;
    const int dc = idx >> 12;                          // [0,64)
    u16x8 v = *(const u16x8*)(vb + (size_t)t * 512 + dc * 8);
#pragma unroll
    for (int j = 0; j < 8; ++j)
      vtb[(size_t)(dc * 8 + j) * 4096 + t] = v[j];
  }
}

// ---------------------------------------------------------------------------
// MFMA flash attention v3. Causal, GQA (kv head = h>>2).
// Fixed softmax max M=14 (Cauchy-Schwarz: S <= 128*gain/sqrt(128*128) = 11.31
// after rmsnorm, so exp(S-14) never overflows and needs no online max/rescale).
// Per-lane l accumulates across all tiles; one cross-lane reduction at the end.
// K and V both double-buffered + prefetched 1 tile ahead via global_load_lds;
// ONE barrier per 64-key tile (drain covered by a full tile of compute).
// Block = 4 waves = 64 q-rows; q-tile pair (31-p, p) -> uniform 33 tiles.
// LDS 72 KB -> 2 blocks/CU.
// ---------------------------------------------------------------------------
__global__ __launch_bounds__(256) void flash_attn(
    const bf16* __restrict__ Q, const bf16* __restrict__ Kg,
    const bf16* __restrict__ Vtg, bf16* __restrict__ Y)
{
  __shared__ bf16 Ks[2][64 * 128];  // [key][d], XOR-swizzled 16B chunks, 2x16 KB
  __shared__ bf16 Vs[2][128 * 64];  // [d][key], swizzled, 2x16 KB
  __shared__ bf16 Ps[4][16 * 64];   // per-wave P [q][key], swizzled, 8 KB

  const int tid = threadIdx.x, lane = tid & 63, w = tid >> 6;
  const int p = blockIdx.x & 15, bh = blockIdx.x >> 4;
  const int h = bh & 15, b = bh >> 4, kvh = h >> 2;
  const int mfrag = lane & 15, quad = lane >> 4;
  const int m7 = mfrag & 7;

  auto stage_k = [&](int kt, int s) {
#pragma unroll
    for (int g = 0; g < 4; ++g) {
      const int o = g * 4096 + w * 1024 + lane * 16;  // byte offset, 256 B rows
      const int r = o >> 8, c = (o >> 4) & 15;
      const int cs = (c & 8) | ((c ^ (r & 7)) & 7);
      const bf16* src = Kg + ((size_t)(b * 2048 + kt * 64 + r)) * 512 + kvh * 128 + cs * 8;
      GLOAD_LDS16(src, (char*)&Ks[s][0] + g * 4096 + w * 1024);
    }
  };
  auto stage_v = [&](int kt, int s) {
#pragma unroll
    for (int g = 0; g < 4; ++g) {
      const int o = g * 4096 + w * 1024 + lane * 16;  // byte offset, 128 B rows
      const int r = o >> 7, c = (o >> 4) & 7;
      const int cs = (c ^ (r & 7)) & 7;
      const bf16* src = Vtg + ((size_t)(kvh * 128 + r)) * 4096 + b * 2048 + kt * 64 + cs * 8;
      GLOAD_LDS16(src, (char*)&Vs[s][0] + g * 4096 + w * 1024);
    }
  };

  stage_k(0, 0);
  stage_v(0, 0);
  int sb = 0;
  bf16* psw = &Ps[w][0];

  for (int phase = 0; phase < 2; ++phase) {
    const int qt = phase ? p : 31 - p;

    bf16x8 qf[4];
    const bf16* qrow = Q + ((size_t)(b * 2048 + qt * 64 + w * 16 + mfrag)) * 2048 + h * 128;
#pragma unroll
    for (int c = 0; c < 4; ++c) qf[c] = *(const bf16x8*)(qrow + c * 32 + quad * 8);

    f32x4 oacc[8] = {};
    float l_lane[4] = {0.f, 0.f, 0.f, 0.f};
    const int q_base = qt * 64 + w * 16 + quad * 4;

    for (int kt = 0; kt <= qt; ++kt) {
      __syncthreads();  // prefetch into [sb] drained; [sb^1] free for overwrite
      const bool last = (phase == 1) && (kt == qt);
      if (!last) {
        const int nk = kt < qt ? kt + 1 : 0;
        stage_k(nk, sb ^ 1);
        stage_v(nk, sb ^ 1);
      }

      // ---- S = Q K^T  (C-layout: row q = quad*4+r, col key = kc*16+mfrag)
      f32x4 sc[4] = {};
#pragma unroll
      for (int kc = 0; kc < 4; ++kc) {
        const bf16* krow = &Ks[sb][0] + (kc * 16 + mfrag) * 128;
#pragma unroll
        for (int c = 0; c < 4; ++c) {
          const int G = 4 * c + quad;
          const int cs = (G & 8) | ((G ^ m7) & 7);
          bf16x8 kf = *(const bf16x8*)(krow + cs * 8);
          sc[kc] = __builtin_amdgcn_mfma_f32_16x16x32_bf16(qf[c], kf, sc[kc], 0, 0, 0);
        }
      }

      // ---- causal mask (diagonal tile only)
      if (kt == qt) {
        const int kcol0 = kt * 64 + mfrag;
#pragma unroll
        for (int kc = 0; kc < 4; ++kc)
#pragma unroll
          for (int r = 0; r < 4; ++r)
            if (kcol0 + kc * 16 > q_base + r) sc[kc][r] = -1e30f;
      }

      // ---- P = exp(S - 14); per-lane l accumulation (no cross-lane ops!)
#pragma unroll
      for (int kc = 0; kc < 4; ++kc)
#pragma unroll
        for (int r = 0; r < 4; ++r) {
          const float pv = __expf(sc[kc][r] - 14.0f);
          l_lane[r] += pv;
          const int q = quad * 4 + r;
          const int slot = ((2 * kc + (mfrag >> 3)) ^ (q & 7)) & 7;
          psw[q * 64 + slot * 8 + m7] = __float2bfloat16(pv);
        }

      // ---- O += P V  (A = own-wave P rows [q][key], B = Vs rows [d][key])
#pragma unroll
      for (int kh = 0; kh < 2; ++kh) {
        const int Gp = 4 * kh + quad;
        const int sl = (Gp ^ m7) & 7;
        bf16x8 pf = *(const bf16x8*)(psw + mfrag * 64 + sl * 8);
#pragma unroll
        for (int dc = 0; dc < 8; ++dc) {
          bf16x8 vf = *(const bf16x8*)(&Vs[sb][0] + (dc * 16 + mfrag) * 64 + sl * 8);
          oacc[dc] = __builtin_amdgcn_mfma_f32_16x16x32_bf16(pf, vf, oacc[dc], 0, 0, 0);
        }
      }
      sb ^= 1;
    }

    // ---- epilogue: reduce l across the 16 lanes holding each row, store
#pragma unroll
    for (int r = 0; r < 4; ++r) {
      float l = l_lane[r];
      l += __shfl_xor(l, 1, 64);
      l += __shfl_xor(l, 2, 64);
      l += __shfl_xor(l, 4, 64);
      l += __shfl_xor(l, 8, 64);
      const float linv = 1.0f / l;
      const size_t row = (size_t)(b * 2048 + q_base + r);
#pragma unroll
      for (int dc = 0; dc < 8; ++dc)
        Y[row * 2048 + h * 128 + dc * 16 + mfrag] = __float2bfloat16(oacc[dc][r] * linv);
    }
  }
}

// ---------------------------------------------------------------------------
extern "C" void kernel_launch(void* const* d_in, const int* in_sizes, int n_in,
                              void* d_out, int out_size, void* d_ws, size_t ws_size,
                              hipStream_t stream)
{
  const float* x      = (const float*)d_in[0];
  const float* q_w    = (const float*)d_in[1];
  const float* k_w    = (const float*)d_in[2];
  const float* v_w    = (const float*)d_in[3];
  const float* o_w    = (const float*)d_in[4];
  const float* q_gain = (const float*)d_in[5];
  float* out = (float*)d_out;

  // workspace (bf16): xb aliases yb (x dead after QKV GEMM); vtb reuses qwb
  // region (q_w copy dead after QKV GEMM).
  char* ws = (char*)d_ws;
  bf16* xb  = (bf16*)(ws);                   // 4096x2048 = 16 MB
  bf16* yb  = (bf16*)(ws);                   // alias of xb
  bf16* qwb = (bf16*)(ws + (16u << 20));     // 2048x2048 = 8 MB
  bf16* vtb = (bf16*)(ws + (16u << 20));     // 512x4096  = 4 MB (after qwb dead)
  bf16* owb = (bf16*)(ws + (24u << 20));     // 2048x2048 = 8 MB
  bf16* kwb = (bf16*)(ws + (32u << 20));     // 512x2048  = 2 MB
  bf16* vwb = (bf16*)(ws + (34u << 20));     // 512x2048  = 2 MB
  bf16* qb  = (bf16*)(ws + (36u << 20));     // 4096x2048 = 16 MB
  bf16* kb  = (bf16*)(ws + (52u << 20));     // 4096x512  = 4 MB
  bf16* vb  = (bf16*)(ws + (56u << 20));     // 4096x512  = 4 MB  (total 60 MB)

  const dim3 blk(256);
  cvt_all<<<dim3(18432), blk, 0, stream>>>(
      (const float4*)x, (const float4*)q_w, (const float4*)k_w,
      (const float4*)v_w, (const float4*)o_w,
      (ushort4*)xb, (ushort4*)qwb, (ushort4*)kwb, (ushort4*)vwb, (ushort4*)owb);

  gemm_qkv<<<dim3(24, 32), blk, 0, stream>>>(xb, qwb, kwb, vwb, qb, kb, vb, 2048);

  postqkv<<<dim3(21504), blk, 0, stream>>>(
      qb, kb, (const unsigned short*)vb, (unsigned short*)vtb, q_gain);

  flash_attn<<<dim3(512), blk, 0, stream>>>(qb, kb, vtb, yb);

  gemm_bt_f32out<<<dim3(16, 32), blk, 0, stream>>>(yb, owb, out, 2048, 2048);
}